// Round 1
// baseline (3661.307 us; speedup 1.0000x reference)
//
#include <hip/hip_runtime.h>

typedef __bf16 bf16;
typedef __bf16 v8bf __attribute__((ext_vector_type(8)));
typedef float v4f __attribute__((ext_vector_type(4)));

#define B_ 4
#define L_ 1024
#define D_ 1024
#define H_ 16
#define DK_ 64

// ---------------------------------------------------------------------------
// Weight transpose (fp32 [K][N] -> bf16 [N][K]) for 5 weights + Er bf16 convert
// ---------------------------------------------------------------------------
__global__ __launch_bounds__(256) void wconv_kernel(
    const float* __restrict__ w0, const float* __restrict__ w1,
    const float* __restrict__ w2, const float* __restrict__ w3,
    const float* __restrict__ w4, const float* __restrict__ er,
    bf16* __restrict__ wt, bf16* __restrict__ erb)
{
    int z = blockIdx.z;
    int tx = threadIdx.x, ty = threadIdx.y;   // block (32, 8)
    if (z < 5) {
        const float* src = z == 0 ? w0 : z == 1 ? w1 : z == 2 ? w2 : z == 3 ? w3 : w4;
        bf16* dst = wt + (size_t)z * 1024 * 1024;
        __shared__ float t[32][33];
        int bx = blockIdx.x * 32, by = blockIdx.y * 32;
#pragma unroll
        for (int i = 0; i < 4; i++)
            t[ty + i * 8][tx] = src[(size_t)(by + ty + i * 8) * 1024 + bx + tx];
        __syncthreads();
#pragma unroll
        for (int i = 0; i < 4; i++)
            dst[(size_t)(bx + ty + i * 8) * 1024 + by + tx] = (bf16)t[tx][ty + i * 8];
    } else {
        int base = (blockIdx.y * 32 + blockIdx.x) * 256 + ty * 32 + tx;
#pragma unroll
        for (int i = 0; i < 4; i++) {
            int idx = base + i * 262144;      // 4*262144 = 1M = H*L*DK
            erb[idx] = (bf16)er[idx];
        }
    }
}

// ---------------------------------------------------------------------------
// C[M,N] = A[M,K] * B[K,N], with B supplied transposed (Bt[N][K], bf16).
// A is fp32 (Af) or bf16 (Ab). C written fp32 (Cf) or bf16 (Cb).
// 64x64 tile, BK=32, MFMA 16x16x32 bf16, 4 waves (one 16-row strip each).
// ---------------------------------------------------------------------------
__global__ __launch_bounds__(256) void gemm_bt(
    const float* __restrict__ Af, const bf16* __restrict__ Ab,
    const bf16* __restrict__ Bt, float* __restrict__ Cf, bf16* __restrict__ Cb,
    int M, int N, int K)
{
    __shared__ bf16 As[64][40];   // +8 pad, rows 80B (16B-aligned)
    __shared__ bf16 Bs[64][40];
    int tid = threadIdx.x;
    int lane = tid & 63;
    int w = tid >> 6;
    int tm = blockIdx.y * 64, tn = blockIdx.x * 64;

    v4f acc[4];
#pragma unroll
    for (int t = 0; t < 4; t++)
#pragma unroll
        for (int i = 0; i < 4; i++) acc[t][i] = 0.f;

    int sr = tid >> 2;            // staging row 0..63
    int sc = (tid & 3) * 8;       // staging col {0,8,16,24}
    int m15 = lane & 15;
    int kq = (lane >> 4) * 8;     // k-chunk within fragment

    for (int k0 = 0; k0 < K; k0 += 32) {
        if (Af) {
            const float* ap = Af + (size_t)(tm + sr) * K + k0 + sc;
            union { bf16 h[8]; uint4 u; } tmp;
#pragma unroll
            for (int j = 0; j < 8; j++) tmp.h[j] = (bf16)ap[j];
            *(uint4*)(&As[sr][sc]) = tmp.u;
        } else {
            *(uint4*)(&As[sr][sc]) = *(const uint4*)(Ab + (size_t)(tm + sr) * K + k0 + sc);
        }
        *(uint4*)(&Bs[sr][sc]) = *(const uint4*)(Bt + (size_t)(tn + sr) * K + k0 + sc);
        __syncthreads();

        // A frag: lane holds A[m=lane&15][k=(lane>>4)*8 + j]
        v8bf a = *(const v8bf*)(&As[w * 16 + m15][kq]);
#pragma unroll
        for (int t = 0; t < 4; t++) {
            v8bf bfrag = *(const v8bf*)(&Bs[t * 16 + m15][kq]);
            acc[t] = __builtin_amdgcn_mfma_f32_16x16x32_bf16(a, bfrag, acc[t], 0, 0, 0);
        }
        __syncthreads();
    }

    // C/D layout: col = lane&15, row = (lane>>4)*4 + reg
    int rq = lane >> 4;
#pragma unroll
    for (int t = 0; t < 4; t++) {
#pragma unroll
        for (int i = 0; i < 4; i++) {
            int row = tm + w * 16 + rq * 4 + i;
            int col = tn + t * 16 + m15;
            if (Cf) Cf[(size_t)row * N + col] = acc[t][i];
            else    Cb[(size_t)row * N + col] = (bf16)acc[t][i];
        }
    }
}

// ---------------------------------------------------------------------------
// Attention: one block per (b, h, qi). Full score row in LDS; single softmax.
// rel skew: score(k) += q2 . Er[h][L-1-qi+k]  (valid for k <= qi)
// Writes p (normalized, zeros above diagonal) and attn_out (bf16).
// ---------------------------------------------------------------------------
__global__ __launch_bounds__(256) void attn_kernel(
    const bf16* __restrict__ qb, const bf16* __restrict__ q2b,
    const bf16* __restrict__ kb, const bf16* __restrict__ vb,
    const bf16* __restrict__ erb, float* __restrict__ p_out,
    bf16* __restrict__ ab)
{
    int qi = blockIdx.x, h = blockIdx.y, b = blockIdx.z;
    int tid = threadIdx.x, lane = tid & 63, w = tid >> 6;
    __shared__ float s[L_];
    __shared__ float qv[DK_], q2v[DK_];
    __shared__ float pvs[4][DK_];
    __shared__ float redm[4], reds[4];

    size_t qoff = (size_t)(b * L_ + qi) * (H_ * DK_) + h * DK_;
    if (tid < DK_)           qv[tid] = (float)qb[qoff + tid];
    else if (tid < 2 * DK_)  q2v[tid - DK_] = (float)q2b[qoff + (tid - DK_)];
    __syncthreads();

    float lmax = -1e30f;
    for (int k = tid; k < L_; k += 256) {
        if (k <= qi) {
            const v8bf* kp = (const v8bf*)(kb + (size_t)(b * L_ + k) * (H_ * DK_) + h * DK_);
            const v8bf* ep = (const v8bf*)(erb + ((size_t)h * L_ + (L_ - 1 - qi + k)) * DK_);
            float d1 = 0.f, d2 = 0.f;
#pragma unroll
            for (int j = 0; j < 8; j++) {
                v8bf kv = kp[j], ev = ep[j];
#pragma unroll
                for (int u = 0; u < 8; u++) {
                    d1 += qv[j * 8 + u] * (float)kv[u];
                    d2 += q2v[j * 8 + u] * (float)ev[u];
                }
            }
            float sc = (d1 + d2) * 0.125f;   // 1/sqrt(DK)
            s[k] = sc;
            lmax = fmaxf(lmax, sc);
        }
    }
#pragma unroll
    for (int off = 32; off; off >>= 1) lmax = fmaxf(lmax, __shfl_xor(lmax, off));
    if (lane == 0) redm[w] = lmax;
    __syncthreads();
    float mx = fmaxf(fmaxf(redm[0], redm[1]), fmaxf(redm[2], redm[3]));

    float lsum = 0.f;
    for (int k = tid; k < L_; k += 256) {
        float e = (k <= qi) ? __expf(s[k] - mx) : 0.f;
        s[k] = e;
        lsum += e;
    }
#pragma unroll
    for (int off = 32; off; off >>= 1) lsum += __shfl_xor(lsum, off);
    if (lane == 0) reds[w] = lsum;
    __syncthreads();
    float rnorm = 1.f / (reds[0] + reds[1] + reds[2] + reds[3]);

    float* prow = p_out + ((size_t)(h * B_ + b) * L_ + qi) * L_;
    for (int k = tid; k < L_; k += 256) {
        float pn = s[k] * rnorm;
        s[k] = pn;
        prow[k] = pn;        // exact 0 above the diagonal
    }
    __syncthreads();

    // PV: wave w handles keys k ≡ w (mod 4); lane = output dim
    float acc = 0.f;
    const bf16* vbase = vb + (size_t)b * L_ * (H_ * DK_) + h * DK_ + lane;
    for (int k = w; k <= qi; k += 4)
        acc += s[k] * (float)vbase[(size_t)k * (H_ * DK_)];
    pvs[w][lane] = acc;
    __syncthreads();
    if (tid < DK_) {
        float o = pvs[0][tid] + pvs[1][tid] + pvs[2][tid] + pvs[3][tid];
        ab[qoff + tid] = (bf16)o;
    }
}

// ---------------------------------------------------------------------------
// y = LayerNorm(y0 + residual) * g + b   (biased variance, eps 1e-5)
// ---------------------------------------------------------------------------
__global__ __launch_bounds__(256) void ln_kernel(
    const float* __restrict__ y0, const float* __restrict__ res,
    const float* __restrict__ g, const float* __restrict__ bb,
    float* __restrict__ y)
{
    int row = blockIdx.x, tid = threadIdx.x, lane = tid & 63, w = tid >> 6;
    __shared__ float rs[4], rq2[4];
    const float* xr = y0 + (size_t)row * D_;
    const float* rr = res + (size_t)row * D_;
    float x[4], sum = 0.f, sq = 0.f;
#pragma unroll
    for (int i = 0; i < 4; i++) {
        int c = tid + i * 256;
        x[i] = xr[c] + rr[c];
        sum += x[i]; sq += x[i] * x[i];
    }
#pragma unroll
    for (int off = 32; off; off >>= 1) { sum += __shfl_xor(sum, off); sq += __shfl_xor(sq, off); }
    if (lane == 0) { rs[w] = sum; rq2[w] = sq; }
    __syncthreads();
    sum = rs[0] + rs[1] + rs[2] + rs[3];
    sq  = rq2[0] + rq2[1] + rq2[2] + rq2[3];
    float mean = sum * (1.f / D_);
    float var  = sq * (1.f / D_) - mean * mean;
    float inv  = rsqrtf(var + 1e-5f);
#pragma unroll
    for (int i = 0; i < 4; i++) {
        int c = tid + i * 256;
        y[(size_t)row * D_ + c] = (x[i] - mean) * inv * g[c] + bb[c];
    }
}

extern "C" void kernel_launch(void* const* d_in, const int* in_sizes, int n_in,
                              void* d_out, int out_size, void* d_ws, size_t ws_size,
                              hipStream_t stream)
{
    const float* q_in = (const float*)d_in[0];
    const float* k_in = (const float*)d_in[1];
    const float* v_in = (const float*)d_in[2];
    const float* Wq   = (const float*)d_in[3];
    const float* Wq2  = (const float*)d_in[4];
    const float* Wk   = (const float*)d_in[5];
    const float* Wv   = (const float*)d_in[6];
    const float* Wo   = (const float*)d_in[7];
    const float* ln_g = (const float*)d_in[8];
    const float* ln_b = (const float*)d_in[9];
    const float* Er   = (const float*)d_in[10];
    // d_in[11] = mask: triu causal, identical across batch -> hard-coded

    float* y_out = (float*)d_out;                       // [B,L,D]
    float* p_out = y_out + (size_t)B_ * L_ * D_;        // [H,B,L,L]

    char* ws = (char*)d_ws;
    const size_t MB = 1024 * 1024;
    bf16*  wT  = (bf16*)(ws);             // 5 x 1M bf16 transposed weights (10 MB)
    bf16*  erb = (bf16*)(ws + 10 * MB);   // 1M bf16 (2 MB)
    bf16*  qb  = (bf16*)(ws + 12 * MB);   // 4M bf16 (8 MB)
    bf16*  q2b = (bf16*)(ws + 20 * MB);
    bf16*  kb  = (bf16*)(ws + 28 * MB);
    bf16*  vb  = (bf16*)(ws + 36 * MB);
    bf16*  ab  = (bf16*)(ws + 44 * MB);   // attention output bf16
    float* y0  = (float*)(ws + 52 * MB);  // fp32 pre-LN (16 MB) -> total 68 MB

    wconv_kernel<<<dim3(32, 32, 6), dim3(32, 8), 0, stream>>>(Wq, Wq2, Wk, Wv, Wo, Er, wT, erb);

    gemm_bt<<<dim3(16, 64), 256, 0, stream>>>(q_in, nullptr, wT + 0 * MB, nullptr, qb,  4096, 1024, 1024);
    gemm_bt<<<dim3(16, 64), 256, 0, stream>>>(q_in, nullptr, wT + 1 * MB, nullptr, q2b, 4096, 1024, 1024);
    gemm_bt<<<dim3(16, 64), 256, 0, stream>>>(k_in, nullptr, wT + 2 * MB, nullptr, kb,  4096, 1024, 1024);
    gemm_bt<<<dim3(16, 64), 256, 0, stream>>>(v_in, nullptr, wT + 3 * MB, nullptr, vb,  4096, 1024, 1024);

    attn_kernel<<<dim3(L_, H_, B_), 256, 0, stream>>>(qb, q2b, kb, vb, erb, p_out, ab);

    gemm_bt<<<dim3(16, 64), 256, 0, stream>>>(nullptr, ab, wT + 4 * MB, y0, nullptr, 4096, 1024, 1024);
    ln_kernel<<<4096, 256, 0, stream>>>(y0, q_in, ln_g, ln_b, y_out);
}

// Round 3
// 1165.328 us; speedup vs baseline: 3.1419x; 3.1419x over previous
//
#include <hip/hip_runtime.h>

typedef __bf16 bf16;
typedef __bf16 v8bf __attribute__((ext_vector_type(8)));
typedef float v4f __attribute__((ext_vector_type(4)));
typedef unsigned int v4u __attribute__((ext_vector_type(4)));

#define B_ 4
#define L_ 1024
#define D_ 1024
#define H_ 16
#define DK_ 64
#define NEG (-3.0e38f)
#define MFMA16(a, b, c) __builtin_amdgcn_mfma_f32_16x16x32_bf16(a, b, c, 0, 0, 0)

// ---------------------------------------------------------------------------
// Weight transpose (fp32 [K][N] -> bf16 [N][K]) for 5 weights + Er bf16 convert
// ---------------------------------------------------------------------------
__global__ __launch_bounds__(256) void wconv_kernel(
    const float* __restrict__ w0, const float* __restrict__ w1,
    const float* __restrict__ w2, const float* __restrict__ w3,
    const float* __restrict__ w4, const float* __restrict__ er,
    bf16* __restrict__ wt, bf16* __restrict__ erb)
{
    int z = blockIdx.z;
    int tx = threadIdx.x, ty = threadIdx.y;   // block (32, 8)
    if (z < 5) {
        const float* src = z == 0 ? w0 : z == 1 ? w1 : z == 2 ? w2 : z == 3 ? w3 : w4;
        bf16* dst = wt + (size_t)z * 1024 * 1024;
        __shared__ float t[32][33];
        int bx = blockIdx.x * 32, by = blockIdx.y * 32;
#pragma unroll
        for (int i = 0; i < 4; i++)
            t[ty + i * 8][tx] = src[(size_t)(by + ty + i * 8) * 1024 + bx + tx];
        __syncthreads();
#pragma unroll
        for (int i = 0; i < 4; i++)
            dst[(size_t)(bx + ty + i * 8) * 1024 + by + tx] = (bf16)t[tx][ty + i * 8];
    } else {
        int base = (blockIdx.y * 32 + blockIdx.x) * 256 + ty * 32 + tx;
#pragma unroll
        for (int i = 0; i < 4; i++) {
            int idx = base + i * 262144;      // 4*262144 = 1M = H*L*DK
            erb[idx] = (bf16)er[idx];
        }
    }
}

// ---------------------------------------------------------------------------
// C[M,N] = A[M,K] * B[K,N], B supplied transposed (Bt[N][K], bf16).
// A fp32 (Af) or bf16 (Ab). mode 0: C bf16 row-major; mode 1: C fp32;
// mode 2: C bf16 written "vt" layout [b][h][dv][l] (for V projection).
// ---------------------------------------------------------------------------
__global__ __launch_bounds__(256) void gemm_bt(
    const float* __restrict__ Af, const bf16* __restrict__ Ab,
    const bf16* __restrict__ Bt, float* __restrict__ Cf, bf16* __restrict__ Cb,
    int M, int N, int K, int mode)
{
    __shared__ __align__(16) bf16 As[64][40];   // 80B rows
    __shared__ __align__(16) bf16 Bs[64][40];
    int tid = threadIdx.x;
    int lane = tid & 63;
    int w = tid >> 6;
    int tm = blockIdx.y * 64, tn = blockIdx.x * 64;

    v4f acc[4];
#pragma unroll
    for (int t = 0; t < 4; t++)
#pragma unroll
        for (int i = 0; i < 4; i++) acc[t][i] = 0.f;

    int sr = tid >> 2;            // staging row 0..63
    int sc = (tid & 3) * 8;       // staging col {0,8,16,24}
    int m15 = lane & 15;
    int kq = (lane >> 4) * 8;

    for (int k0 = 0; k0 < K; k0 += 32) {
        if (Af) {
            const float* ap = Af + (size_t)(tm + sr) * K + k0 + sc;
            union { bf16 h[8]; uint4 u; } tmp;
#pragma unroll
            for (int j = 0; j < 8; j++) tmp.h[j] = (bf16)ap[j];
            *(uint4*)(&As[sr][sc]) = tmp.u;
        } else {
            *(uint4*)(&As[sr][sc]) = *(const uint4*)(Ab + (size_t)(tm + sr) * K + k0 + sc);
        }
        *(uint4*)(&Bs[sr][sc]) = *(const uint4*)(Bt + (size_t)(tn + sr) * K + k0 + sc);
        __syncthreads();

        v8bf a = *(const v8bf*)(&As[w * 16 + m15][kq]);
#pragma unroll
        for (int t = 0; t < 4; t++) {
            v8bf bfrag = *(const v8bf*)(&Bs[t * 16 + m15][kq]);
            acc[t] = MFMA16(a, bfrag, acc[t]);
        }
        __syncthreads();
    }

    int rq = lane >> 4;
#pragma unroll
    for (int t = 0; t < 4; t++) {
#pragma unroll
        for (int i = 0; i < 4; i++) {
            int row = tm + w * 16 + rq * 4 + i;
            int col = tn + t * 16 + m15;
            if (mode == 1)      Cf[(size_t)row * N + col] = acc[t][i];
            else if (mode == 0) Cb[(size_t)row * N + col] = (bf16)acc[t][i];
            else {
                // row = b*1024 + l ; col = h*64 + dv  ->  vt[((b*16+h)*64+dv)*1024 + l]
                int bb = row >> 10, l = row & 1023, hh = col >> 6, dv = col & 63;
                Cb[(((size_t)(bb * 16 + hh) * 64 + dv) << 10) + l] = (bf16)acc[t][i];
            }
        }
    }
}

// ---------------------------------------------------------------------------
// rel[q][k] = q2[q] . Er[1023 - q + k]  written as fp32 into the p-output
// region at [h*4+b][q][k] (k in [0,q]).  GEMM over (q x r) with skewed store:
// k = r - 1023 + q.
// ---------------------------------------------------------------------------
__global__ __launch_bounds__(256) void rel_gemm(
    const bf16* __restrict__ q2b, const bf16* __restrict__ erb,
    float* __restrict__ p_out)
{
    int qt = 15 - (int)blockIdx.x;            // heavy blocks first
    int h = blockIdx.y, b = blockIdx.z;
    int q0 = qt << 6;
    int tid = threadIdx.x, lane = tid & 63, w = tid >> 6;
    int m15 = lane & 15, rq = lane >> 4, kq = rq * 8;
    __shared__ __align__(16) bf16 Q2s[64][72];
    __shared__ __align__(16) bf16 Ers[64][72];

    for (int c = tid; c < 512; c += 256) {
        int r = c >> 3, col = (c & 7) * 8;
        *(uint4*)&Q2s[r][col] =
            *(const uint4*)&q2b[((size_t)((b << 10) + q0 + r) * 16 + h) * 64 + col];
    }
    __syncthreads();
    v8bf alo = *(const v8bf*)&Q2s[w * 16 + m15][kq];
    v8bf ahi = *(const v8bf*)&Q2s[w * 16 + m15][kq + 32];
    size_t pb = (size_t)(h * 4 + b) << 20;

    for (int rt = 15 - qt; rt < 16; ++rt) {
        int r0 = rt << 6;
        __syncthreads();
        for (int c = tid; c < 512; c += 256) {
            int r = c >> 3, col = (c & 7) * 8;
            *(uint4*)&Ers[r][col] = *(const uint4*)&erb[((size_t)h * 1024 + r0 + r) * 64 + col];
        }
        __syncthreads();
#pragma unroll
        for (int ct = 0; ct < 4; ++ct) {
            v4f acc = {0.f, 0.f, 0.f, 0.f};
            v8bf blo = *(const v8bf*)&Ers[ct * 16 + m15][kq];
            v8bf bhi = *(const v8bf*)&Ers[ct * 16 + m15][kq + 32];
            acc = MFMA16(alo, blo, acc);
            acc = MFMA16(ahi, bhi, acc);
#pragma unroll
            for (int i = 0; i < 4; ++i) {
                int q = q0 + w * 16 + rq * 4 + i;
                int r = r0 + ct * 16 + m15;
                int k = r - 1023 + q;
                if (k >= 0)
                    __builtin_nontemporal_store(acc[i], &p_out[pb + ((size_t)q << 10) + k]);
            }
        }
    }
}

// ---------------------------------------------------------------------------
// Zero the strictly-upper 64x64 tiles of p (kt > qt); the diagonal tile's
// masked entries are written as exact zeros by attn pass 2.
// ---------------------------------------------------------------------------
__global__ __launch_bounds__(256) void zero_upper(float* __restrict__ p)
{
    int kt = blockIdx.x + 1;   // 1..15
    int qt = blockIdx.y;
    if (kt <= qt) return;
    int bh = blockIdx.z;
    int r = threadIdx.x >> 2;
    int cg = (threadIdx.x & 3) * 16;
    float* base = p + ((size_t)bh << 20) + ((size_t)(qt * 64 + r) << 10) + kt * 64 + cg;
    v4f z = {0.f, 0.f, 0.f, 0.f};
#pragma unroll
    for (int i = 0; i < 4; ++i)
        __builtin_nontemporal_store(z, (v4f*)(base + i * 4));
}

// ---------------------------------------------------------------------------
// Flash-style MFMA attention. One block per (b,h,64-row q-tile), 4 waves,
// each wave owns a 16-row strip (row softmax reductions are 16-lane shfls).
// Pass 1: scores -> running (m,l). Pass 2: recompute scores, write normalized
// p (overwriting the rel values staged there), accumulate O = P.V by MFMA.
// ---------------------------------------------------------------------------
__global__ __launch_bounds__(256) void attn_mfma(
    const bf16* __restrict__ qb, const bf16* __restrict__ kb,
    const bf16* __restrict__ vt, float* __restrict__ p_out,
    bf16* __restrict__ ab)
{
    int qt = 15 - (int)blockIdx.x;
    int h = blockIdx.y, b = blockIdx.z;
    int q0 = qt << 6;
    int tid = threadIdx.x, lane = tid & 63, w = tid >> 6;
    int m15 = lane & 15, rq = lane >> 4, kq = rq * 8;
    int li0 = w * 16 + rq * 4;

    __shared__ __align__(16) bf16 Qs[64][72];
    __shared__ __align__(16) bf16 Ks[64][72];
    __shared__ __align__(16) bf16 Vts[64][72];
    __shared__ __align__(16) bf16 Ps[64][72];
    __shared__ __align__(16) float RELs[64][68];

    for (int c = tid; c < 512; c += 256) {
        int r = c >> 3, col = (c & 7) * 8;
        *(uint4*)&Qs[r][col] =
            *(const uint4*)&qb[((size_t)((b << 10) + q0 + r) * 16 + h) * 64 + col];
    }
    __syncthreads();
    v8bf alo = *(const v8bf*)&Qs[w * 16 + m15][kq];
    v8bf ahi = *(const v8bf*)&Qs[w * 16 + m15][kq + 32];

    float m_run[4], l_run[4], linv[4];
#pragma unroll
    for (int i = 0; i < 4; ++i) { m_run[i] = NEG; l_run[i] = 0.f; }
    v4f oacc[4];
#pragma unroll
    for (int t = 0; t < 4; ++t)
#pragma unroll
        for (int i = 0; i < 4; ++i) oacc[t][i] = 0.f;

    size_t pb = (size_t)(h * 4 + b) << 20;
    size_t kbase = ((size_t)(b << 10) * 16 + h) * 64;       // + k*1024 + d
    size_t vbase = ((size_t)(b * 16 + h) << 16);            // vt[(b*16+h)*64*1024]
    int nkt = qt + 1;

    for (int pass = 0; pass < 2; ++pass) {
        if (pass) {
#pragma unroll
            for (int i = 0; i < 4; ++i) linv[i] = 1.f / l_run[i];
        }
        for (int kt = 0; kt < nkt; ++kt) {
            int k0 = kt << 6;
            __syncthreads();   // protect LDS from previous iteration's readers
            for (int c = tid; c < 512; c += 256) {
                int r = c >> 3, col = (c & 7) * 8;
                *(uint4*)&Ks[r][col] =
                    *(const uint4*)&kb[kbase + ((size_t)(k0 + r) << 6) * 16 + col];
                if (pass)
                    *(uint4*)&Vts[r][col] =
                        *(const uint4*)&vt[vbase + ((size_t)r << 10) + k0 + col];
            }
            for (int c = tid; c < 1024; c += 256) {
                int r = c >> 4, col = (c & 15) * 4;
                v4u rel = __builtin_nontemporal_load(
                    (const v4u*)&p_out[pb + ((size_t)(q0 + r) << 10) + k0 + col]);
                *(v4u*)&RELs[r][col] = rel;
            }
            __syncthreads();

            // QK^T: 4 col-tiles of 16 k-indices
            v4f qk[4];
#pragma unroll
            for (int ct = 0; ct < 4; ++ct) {
                v4f acc = {0.f, 0.f, 0.f, 0.f};
                v8bf blo = *(const v8bf*)&Ks[ct * 16 + m15][kq];
                v8bf bhi = *(const v8bf*)&Ks[ct * 16 + m15][kq + 32];
                acc = MFMA16(alo, blo, acc);
                qk[ct] = MFMA16(ahi, bhi, acc);
            }
            float sc[4][4];
#pragma unroll
            for (int ct = 0; ct < 4; ++ct)
#pragma unroll
                for (int i = 0; i < 4; ++i) {
                    int li = li0 + i;
                    int j = ct * 16 + m15;
                    float v = (qk[ct][i] + RELs[li][j]) * 0.125f;
                    sc[ct][i] = (k0 + j > q0 + li) ? NEG : v;
                }
            if (!pass) {
#pragma unroll
                for (int i = 0; i < 4; ++i) {
                    float tmax = fmaxf(fmaxf(sc[0][i], sc[1][i]), fmaxf(sc[2][i], sc[3][i]));
#pragma unroll
                    for (int off = 1; off < 16; off <<= 1)
                        tmax = fmaxf(tmax, __shfl_xor(tmax, off));
                    float mn = fmaxf(m_run[i], tmax);
                    float es = __expf(sc[0][i] - mn) + __expf(sc[1][i] - mn)
                             + __expf(sc[2][i] - mn) + __expf(sc[3][i] - mn);
#pragma unroll
                    for (int off = 1; off < 16; off <<= 1)
                        es += __shfl_xor(es, off);
                    l_run[i] = l_run[i] * __expf(m_run[i] - mn) + es;
                    m_run[i] = mn;
                }
            } else {
#pragma unroll
                for (int ct = 0; ct < 4; ++ct)
#pragma unroll
                    for (int i = 0; i < 4; ++i) {
                        int li = li0 + i;
                        int j = ct * 16 + m15;
                        float p = __expf(sc[ct][i] - m_run[i]) * linv[i];
                        __builtin_nontemporal_store(
                            p, &p_out[pb + ((size_t)(q0 + li) << 10) + k0 + j]);
                        Ps[li][j] = (bf16)p;
                    }
                // P.V  (Ps rows are wave-local: no barrier needed)
                v8bf plo = *(const v8bf*)&Ps[w * 16 + m15][kq];
                v8bf phi = *(const v8bf*)&Ps[w * 16 + m15][kq + 32];
#pragma unroll
                for (int ct = 0; ct < 4; ++ct) {
                    v8bf blo = *(const v8bf*)&Vts[ct * 16 + m15][kq];
                    v8bf bhi = *(const v8bf*)&Vts[ct * 16 + m15][kq + 32];
                    oacc[ct] = MFMA16(plo, blo, oacc[ct]);
                    oacc[ct] = MFMA16(phi, bhi, oacc[ct]);
                }
            }
        }
    }

#pragma unroll
    for (int ct = 0; ct < 4; ++ct)
#pragma unroll
        for (int i = 0; i < 4; ++i)
            ab[((size_t)((b << 10) + q0 + li0 + i) * 16 + h) * 64 + ct * 16 + m15] =
                (bf16)oacc[ct][i];
}

// ---------------------------------------------------------------------------
// y = LayerNorm(y0 + residual) * g + b   (biased variance, eps 1e-5)
// ---------------------------------------------------------------------------
__global__ __launch_bounds__(256) void ln_kernel(
    const float* __restrict__ y0, const float* __restrict__ res,
    const float* __restrict__ g, const float* __restrict__ bb,
    float* __restrict__ y)
{
    int row = blockIdx.x, tid = threadIdx.x, lane = tid & 63, w = tid >> 6;
    __shared__ float rs[4], rq2[4];
    const float* xr = y0 + (size_t)row * D_;
    const float* rr = res + (size_t)row * D_;
    float x[4], sum = 0.f, sq = 0.f;
#pragma unroll
    for (int i = 0; i < 4; i++) {
        int c = tid + i * 256;
        x[i] = xr[c] + rr[c];
        sum += x[i]; sq += x[i] * x[i];
    }
#pragma unroll
    for (int off = 32; off; off >>= 1) { sum += __shfl_xor(sum, off); sq += __shfl_xor(sq, off); }
    if (lane == 0) { rs[w] = sum; rq2[w] = sq; }
    __syncthreads();
    sum = rs[0] + rs[1] + rs[2] + rs[3];
    sq  = rq2[0] + rq2[1] + rq2[2] + rq2[3];
    float mean = sum * (1.f / D_);
    float var  = sq * (1.f / D_) - mean * mean;
    float inv  = rsqrtf(var + 1e-5f);
#pragma unroll
    for (int i = 0; i < 4; i++) {
        int c = tid + i * 256;
        y[(size_t)row * D_ + c] = (x[i] - mean) * inv * g[c] + bb[c];
    }
}

extern "C" void kernel_launch(void* const* d_in, const int* in_sizes, int n_in,
                              void* d_out, int out_size, void* d_ws, size_t ws_size,
                              hipStream_t stream)
{
    const float* q_in = (const float*)d_in[0];
    const float* k_in = (const float*)d_in[1];
    const float* v_in = (const float*)d_in[2];
    const float* Wq   = (const float*)d_in[3];
    const float* Wq2  = (const float*)d_in[4];
    const float* Wk   = (const float*)d_in[5];
    const float* Wv   = (const float*)d_in[6];
    const float* Wo   = (const float*)d_in[7];
    const float* ln_g = (const float*)d_in[8];
    const float* ln_b = (const float*)d_in[9];
    const float* Er   = (const float*)d_in[10];
    // d_in[11] = mask: triu causal, identical across batch -> hard-coded

    float* y_out = (float*)d_out;                       // [B,L,D]
    float* p_out = y_out + (size_t)B_ * L_ * D_;        // [H,B,L,L]

    char* ws = (char*)d_ws;
    const size_t MB = 1024 * 1024;
    bf16*  wT  = (bf16*)(ws);             // 5 x 1M bf16 transposed weights (10 MB)
    bf16*  erb = (bf16*)(ws + 10 * MB);   // 1M bf16 (2 MB)
    bf16*  qb  = (bf16*)(ws + 12 * MB);   // [b][l][h][dk] (8 MB)
    bf16*  q2b = (bf16*)(ws + 20 * MB);
    bf16*  kb  = (bf16*)(ws + 28 * MB);
    bf16*  vtb = (bf16*)(ws + 36 * MB);   // V transposed [b][h][dv][l]
    bf16*  ab  = (bf16*)(ws + 44 * MB);   // attention output [b][l][h][dv]
    float* y0  = (float*)(ws + 52 * MB);  // fp32 pre-LN (16 MB) -> total 68 MB

    wconv_kernel<<<dim3(32, 32, 6), dim3(32, 8), 0, stream>>>(Wq, Wq2, Wk, Wv, Wo, Er, wT, erb);

    gemm_bt<<<dim3(16, 64), 256, 0, stream>>>(q_in, nullptr, wT + 0 * MB, nullptr, qb,  4096, 1024, 1024, 0);
    gemm_bt<<<dim3(16, 64), 256, 0, stream>>>(q_in, nullptr, wT + 1 * MB, nullptr, q2b, 4096, 1024, 1024, 0);
    gemm_bt<<<dim3(16, 64), 256, 0, stream>>>(k_in, nullptr, wT + 2 * MB, nullptr, kb,  4096, 1024, 1024, 0);
    gemm_bt<<<dim3(16, 64), 256, 0, stream>>>(v_in, nullptr, wT + 3 * MB, nullptr, vtb, 4096, 1024, 1024, 2);

    rel_gemm<<<dim3(16, 16, 4), 256, 0, stream>>>(q2b, erb, p_out);
    zero_upper<<<dim3(15, 16, 64), 256, 0, stream>>>(p_out);
    attn_mfma<<<dim3(16, 16, 4), 256, 0, stream>>>(qb, kb, vtb, p_out, ab);

    gemm_bt<<<dim3(16, 64), 256, 0, stream>>>(nullptr, ab, wT + 4 * MB, y0, nullptr, 4096, 1024, 1024, 1);
    ln_kernel<<<4096, 256, 0, stream>>>(y0, q_in, ln_g, ln_b, y_out);
}